// Round 2
// baseline (1979.960 us; speedup 1.0000x reference)
//
#include <hip/hip_runtime.h>
#include <math.h>

#define TT   100
#define BSZ  2048
#define NCH  4
#define CT   (TT/NCH)        /* 25 steps per chunk */
#define CR   (CT*BSZ)        /* 51200 (t,b) rows per chunk */
#define DR   ((TT+1)*BSZ)
#define EPSV 1e-4f

typedef short bfrag __attribute__((ext_vector_type(8)));  /* 8 bf16 (4 VGPR) */
typedef float facc  __attribute__((ext_vector_type(4)));  /* 4 f32 acc */

static __device__ __forceinline__ short f2b(float x){
  union { float f; unsigned u; } c; c.f = x;
  unsigned r = (c.u + 0x7FFFu + ((c.u >> 16) & 1u)) >> 16;   /* RNE */
  return (short)r;
}
static __device__ __forceinline__ float b2f(short s){
  union { unsigned u; float f; } c; c.u = ((unsigned)(unsigned short)s) << 16;
  return c.f;
}
static __device__ __forceinline__ facc mfma16(bfrag a, bfrag b, facc c){
  return __builtin_amdgcn_mfma_f32_16x16x32_bf16(a, b, c, 0, 0, 0);
}
static __device__ __forceinline__ float sigm(float x){ return 1.f/(1.f+__expf(-x)); }
static __device__ __forceinline__ float tanh_f(float x){
  x = fminf(fmaxf(x, -15.f), 15.f);
  float e = __expf(2.f*x);
  return (e-1.f)/(e+1.f);
}

/* ---------------- prep kernels ---------------- */
__global__ __launch_bounds__(256) void k_cvt(const float* __restrict__ src, short* __restrict__ dst,
    int N, int K, int stride, int colOff, int Np, int Kp){
  int idx = blockIdx.x*256 + threadIdx.x;
  if (idx >= Np*Kp) return;
  int n = idx / Kp, k = idx - n*Kp;
  float v = (n < N && k < K) ? src[(size_t)n*stride + colOff + k] : 0.f;
  dst[idx] = f2b(v);
}
__global__ __launch_bounds__(256) void k_cvtT(const float* __restrict__ src, float* __restrict__ dst,
    int N, int K, int stride, int colOff, int Np){
  int idx = blockIdx.x*256 + threadIdx.x;
  if (idx >= K*Np) return;
  int k = idx / Np, n = idx - k*Np;
  dst[idx] = (n < N) ? src[(size_t)n*stride + colOff + k] : 0.f;
}
__global__ __launch_bounds__(256) void k_padb(const float* __restrict__ src, float* __restrict__ dst,
    int N, int Np){
  int idx = blockIdx.x*256 + threadIdx.x;
  if (idx < Np) dst[idx] = (idx < N) ? src[idx] : 0.f;
}

/* ---------------- small two-layer MLP over BS rows (VALU fp32) ---------------- */
__global__ __launch_bounds__(256) void k_mlp2(const float* __restrict__ x, int Kin,
    const float* __restrict__ w1, const float* __restrict__ b1,
    const float* __restrict__ w2T, const float* __restrict__ b2,
    int act_tanh,
    float* __restrict__ outf, int outf_stride,
    short* __restrict__ outb){
  int row = blockIdx.x, t = threadIdx.x;
  __shared__ float xr[16];
  __shared__ float h1[200];
  if (t < Kin) xr[t] = x[(size_t)row*Kin + t];
  __syncthreads();
  if (t < 200){
    float a = b1[t];
    #pragma unroll 4
    for (int i = 0; i < Kin; ++i) a += xr[i] * w1[t*Kin + i];
    h1[t] = fmaxf(a, 0.f);
  }
  __syncthreads();
  if (t < 224){
    float v = 0.f;
    if (t < 200){
      float a = b2[t];
      #pragma unroll 4
      for (int k = 0; k < 200; ++k) a += h1[k] * w2T[k*200 + t];
      v = act_tanh ? tanh_f(a) : fmaxf(a, 0.f);
    }
    if (t < outf_stride) outf[(size_t)row*outf_stride + t] = v;
    if (outb) outb[(size_t)row*224 + t] = f2b(v);
  }
}

/* gi_ctx[b][n] = bih[n] + sum_k ctx_embed[b][k] * wih[n][k]  (ctx cols 0..199) */
__global__ __launch_bounds__(256) void k_gictx(const float* __restrict__ ctxe,
    const float* __restrict__ wT, const float* __restrict__ bih, float* __restrict__ gic){
  int b = blockIdx.x, t = threadIdx.x;
  __shared__ float cr[200];
  if (t < 200) cr[t] = ctxe[(size_t)b*200 + t];
  __syncthreads();
  for (int n = t; n < 608; n += 256){
    float a = 0.f;
    if (n < 600){
      a = bih[n];
      #pragma unroll 4
      for (int k = 0; k < 200; ++k) a += cr[k] * wT[k*608 + n];
    }
    gic[(size_t)b*608 + n] = a;
  }
}

/* ---------------- fused: L1(VALU) -> L2(MFMA, in-place LDS) -> gi GEMM ----------------
   64 (t,b) rows per block, one T-chunk per launch. */
__global__ __launch_bounds__(256) void k_fuse(
    const float* __restrict__ u, const float* __restrict__ lc,
    const float* __restrict__ aw1, const float* __restrict__ ab1,
    const float* __restrict__ lw1, const float* __restrict__ lb1,
    const short* __restrict__ aw2b, const float* __restrict__ ab2p,
    const short* __restrict__ lw2b, const float* __restrict__ lb2p,
    const short* __restrict__ wihab, const short* __restrict__ wihlb,
    const float* __restrict__ gic, short* __restrict__ gibuf, int rowBase){
  __shared__ short t1[2][64][224];
  int tid = threadIdx.x;
  int r0 = blockIdx.x * 64;           /* chunk-local row */
  /* stage 1: both L1s, fp32 VALU -> LDS bf16 (K padded to 224 with zeros) */
  for (int e = tid; e < 64*224; e += 256){
    int row = e / 224, k = e - row*224;
    float va = 0.f, vl = 0.f;
    if (k < 200){
      size_t rg = (size_t)rowBase + r0 + row;
      const float* ur = u + rg*4;
      const float* lr = lc + rg*6;
      va = ab1[k];
      #pragma unroll
      for (int i = 0; i < 4; ++i) va += ur[i]*aw1[k*4+i];
      va = fmaxf(va, 0.f);
      vl = lb1[k];
      #pragma unroll
      for (int i = 0; i < 6; ++i) vl += lr[i]*lw1[k*6+i];
      vl = fmaxf(vl, 0.f);
    }
    t1[0][row][k] = f2b(va);
    t1[1][row][k] = f2b(vl);
  }
  __syncthreads();
  int w = tid >> 6, lane = tid & 63, lm = lane & 15, lq = lane >> 4;
  /* stages 2/3: L2 MFMA for each chain, results written back in place */
  for (int ch = 0; ch < 2; ++ch){
    const short* w2b = ch ? lw2b : aw2b;
    const float* b2p = ch ? lb2p : ab2p;
    int nt0 = (w == 0) ? 0 : 4 + 3*(w-1);
    int cnt = (w == 0) ? 4 : 3;
    facc accT[4][4];
    #pragma unroll
    for (int ti = 0; ti < 4; ++ti)
      #pragma unroll
      for (int m = 0; m < 4; ++m)
        accT[ti][m] = (facc){0.f,0.f,0.f,0.f};
    #pragma unroll
    for (int ti = 0; ti < 4; ++ti) if (ti < cnt){
      int col = (nt0+ti)*16 + lm;
      #pragma unroll
      for (int ks = 0; ks < 7; ++ks){
        bfrag bf = *reinterpret_cast<const bfrag*>(&w2b[(size_t)col*224 + ks*32 + lq*8]);
        #pragma unroll
        for (int m = 0; m < 4; ++m){
          bfrag af = *reinterpret_cast<const bfrag*>(&t1[ch][m*16 + lm][ks*32 + lq*8]);
          accT[ti][m] = mfma16(af, bf, accT[ti][m]);
        }
      }
    }
    __syncthreads();   /* all reads of t1[ch] complete -> safe to overwrite */
    #pragma unroll
    for (int ti = 0; ti < 4; ++ti) if (ti < cnt){
      int col = (nt0+ti)*16 + lm;
      float bias = b2p[col];
      #pragma unroll
      for (int m = 0; m < 4; ++m)
        #pragma unroll
        for (int i = 0; i < 4; ++i)
          t1[ch][m*16 + lq*4 + i][col] = f2b(fmaxf(accT[ti][m][i] + bias, 0.f));
    }
    __syncthreads();
  }
  /* stage 4: gi = ae2 @ WihA^T + lce2 @ WihL^T + gi_ctx */
  int nt0 = (w < 2) ? w*10 : 20 + (w-2)*9;
  int cnt = (w < 2) ? 10 : 9;
  for (int nti = 0; nti < cnt; ++nti){
    int col = (nt0+nti)*16 + lm;
    bfrag Ba[7], Bl[7];
    #pragma unroll
    for (int ks = 0; ks < 7; ++ks){
      Ba[ks] = *reinterpret_cast<const bfrag*>(&wihab[(size_t)col*224 + ks*32 + lq*8]);
      Bl[ks] = *reinterpret_cast<const bfrag*>(&wihlb[(size_t)col*224 + ks*32 + lq*8]);
    }
    facc acc[4];
    #pragma unroll
    for (int m = 0; m < 4; ++m) acc[m] = (facc){0.f,0.f,0.f,0.f};
    #pragma unroll
    for (int m = 0; m < 4; ++m){
      #pragma unroll
      for (int ks = 0; ks < 7; ++ks){
        bfrag a = *reinterpret_cast<const bfrag*>(&t1[0][m*16 + lm][ks*32 + lq*8]);
        acc[m] = mfma16(a, Ba[ks], acc[m]);
      }
      #pragma unroll
      for (int ks = 0; ks < 7; ++ks){
        bfrag a = *reinterpret_cast<const bfrag*>(&t1[1][m*16 + lm][ks*32 + lq*8]);
        acc[m] = mfma16(a, Bl[ks], acc[m]);
      }
    }
    #pragma unroll
    for (int m = 0; m < 4; ++m)
      #pragma unroll
      for (int i = 0; i < 4; ++i){
        size_t rl = (size_t)r0 + m*16 + lq*4 + i;          /* chunk-local row */
        int b = (int)(((size_t)rowBase + rl) & 2047);
        float v = acc[m][i] + gic[(size_t)b*608 + col];
        gibuf[rl*608 + col] = f2b(v);
      }
  }
}

/* ---------------- GRU scan chunk: 128 blocks x 512 thr, 16 batch rows/block ----------------
   W_hh fragments persistent in registers; h fp32 in LDS across steps. */
__global__ __launch_bounds__(512, 2) void k_gru_c(
    const short* __restrict__ gib, const float* __restrict__ hin,
    const short* __restrict__ whhb, const float* __restrict__ bhhp,
    short* __restrict__ hidb, float* __restrict__ hout){
  __shared__ float gh[16][608];
  __shared__ float hF[16][200];
  __shared__ short hB[16][224];
  int tid = threadIdx.x;
  int r0 = blockIdx.x * 16;
  int w = tid >> 6, lane = tid & 63, lm = lane & 15, lq = lane >> 4;
  int ntStart = (w < 6) ? w*5 : 30 + (w-6)*4;
  int ntCnt   = (w < 6) ? 5 : 4;
  bfrag B[5][7];
  float bias[5];
  #pragma unroll
  for (int s = 0; s < 5; ++s) if (s < ntCnt){
    int col = (ntStart+s)*16 + lm;
    bias[s] = bhhp[col];
    #pragma unroll
    for (int ks = 0; ks < 7; ++ks)
      B[s][ks] = *reinterpret_cast<const bfrag*>(&whhb[(size_t)col*224 + ks*32 + lq*8]);
  }
  for (int e = tid; e < 16*224; e += 512){
    int row = e / 224, k = e - row*224;
    float v = hin[(size_t)(r0+row)*224 + k];
    if (k < 200) hF[row][k] = v;
    hB[row][k] = f2b(v);
  }
  __syncthreads();
  for (int t = 0; t < CT; ++t){
    /* prefetch gi for this step */
    float pr[7], pz[7], pn[7];
    #pragma unroll
    for (int i = 0; i < 7; ++i){
      int e = tid + i*512;
      if (e < 3200){
        int row = e / 200, j = e - row*200;
        size_t base = ((size_t)t*BSZ + r0 + row)*608 + j;
        pr[i] = b2f(gib[base]);
        pz[i] = b2f(gib[base+200]);
        pn[i] = b2f(gib[base+400]);
      }
    }
    /* gh = h @ whh^T + bhh */
    bfrag hf[7];
    #pragma unroll
    for (int ks = 0; ks < 7; ++ks)
      hf[ks] = *reinterpret_cast<const bfrag*>(&hB[lm][ks*32 + lq*8]);
    #pragma unroll
    for (int s = 0; s < 5; ++s) if (s < ntCnt){
      facc a = {0.f,0.f,0.f,0.f};
      #pragma unroll
      for (int ks = 0; ks < 7; ++ks) a = mfma16(hf[ks], B[s][ks], a);
      int col = (ntStart+s)*16 + lm;
      #pragma unroll
      for (int i = 0; i < 4; ++i) gh[lq*4 + i][col] = a[i] + bias[s];
    }
    __syncthreads();
    /* gates */
    #pragma unroll
    for (int i = 0; i < 7; ++i){
      int e = tid + i*512;
      if (e < 3200){
        int row = e / 200, j = e - row*200;
        float r = sigm(pr[i] + gh[row][j]);
        float zz = sigm(pz[i] + gh[row][200+j]);
        float n = tanh_f(pn[i] + r * gh[row][400+j]);
        float hn = (1.f - zz)*n + zz*hF[row][j];
        hF[row][j] = hn;
        short hb = f2b(hn);
        hB[row][j] = hb;
        hidb[((size_t)(t+1)*BSZ + r0 + row)*224 + j] = hb;
      }
    }
    __syncthreads();
  }
  /* write carry h (fp32, padded) for next chunk */
  for (int e = tid; e < 16*224; e += 512){
    int row = e / 224, k = e - row*224;
    hout[(size_t)(r0+row)*224 + k] = (k < 200) ? hF[row][k] : 0.f;
  }
}

/* ---------------- fused decode + cov heads over one chunk of hiddens ---------------- */
__global__ __launch_bounds__(256) void k_dec(
    const short* __restrict__ hidb, int rowStart, int outBase,
    const short* __restrict__ dw1b, const float* __restrict__ db1p,
    const short* __restrict__ dw2b, const float* __restrict__ db2p,
    const short* __restrict__ cw1b, const float* __restrict__ cb1p,
    const short* __restrict__ cw2b, const float* __restrict__ cb2p,
    float* __restrict__ outMean, float* __restrict__ outStd){
  __shared__ short h1t[64][224];
  int tid = threadIdx.x;
  int r0 = rowStart + blockIdx.x * 64;     /* local row in hidb */
  int w = tid >> 6, lane = tid & 63, lm = lane & 15, lq = lane >> 4;
  for (int e = tid; e < 64*16; e += 256)
    h1t[e >> 4][208 + (e & 15)] = 0;
  bfrag hf[4][7];
  #pragma unroll
  for (int m = 0; m < 4; ++m)
    #pragma unroll
    for (int ks = 0; ks < 7; ++ks)
      hf[m][ks] = *reinterpret_cast<const bfrag*>(&hidb[(size_t)(r0 + m*16 + lm)*224 + ks*32 + lq*8]);
  int ntStart = (w == 0) ? 0 : 4 + 3*(w-1);
  int ntCnt   = (w == 0) ? 4 : 3;
  for (int pass = 0; pass < 2; ++pass){
    const short* w1b = pass ? cw1b : dw1b;
    const float* b1p = pass ? cb1p : db1p;
    const short* w2b = pass ? cw2b : dw2b;
    const float* b2p = pass ? cb2p : db2p;
    __syncthreads();
    for (int nti = 0; nti < ntCnt; ++nti){
      int nt = ntStart + nti;
      int col = nt*16 + lm;
      facc z = {0.f,0.f,0.f,0.f};
      facc acc[4] = {z,z,z,z};
      #pragma unroll
      for (int ks = 0; ks < 7; ++ks){
        bfrag bf = *reinterpret_cast<const bfrag*>(&w1b[(size_t)col*224 + ks*32 + lq*8]);
        #pragma unroll
        for (int m = 0; m < 4; ++m) acc[m] = mfma16(hf[m][ks], bf, acc[m]);
      }
      float bias = b1p[col];
      #pragma unroll
      for (int m = 0; m < 4; ++m)
        #pragma unroll
        for (int i = 0; i < 4; ++i)
          h1t[m*16 + lq*4 + i][col] = f2b(fmaxf(acc[m][i] + bias, 0.f));
    }
    __syncthreads();
    bfrag a2[7];
    #pragma unroll
    for (int ks = 0; ks < 7; ++ks)
      a2[ks] = *reinterpret_cast<const bfrag*>(&h1t[w*16 + lm][ks*32 + lq*8]);
    facc acc = {0.f,0.f,0.f,0.f};
    #pragma unroll
    for (int ks = 0; ks < 7; ++ks){
      bfrag bf = *reinterpret_cast<const bfrag*>(&w2b[(size_t)lm*224 + ks*32 + lq*8]);
      acc = mfma16(a2[ks], bf, acc);
    }
    if (lm < 12){
      float bias = b2p[lm];
      #pragma unroll
      for (int i = 0; i < 4; ++i){
        size_t rg = (size_t)outBase + r0 + w*16 + lq*4 + i;
        float v = acc[i] + bias;
        if (pass){
          float sp = (v > 15.f) ? v : log1pf(__expf(v));
          outStd[rg*12 + lm] = sqrtf(sp + EPSV);
        } else {
          outMean[rg*12 + lm] = v;
        }
      }
    }
  }
}

extern "C" void kernel_launch(void* const* d_in, const int* in_sizes, int n_in,
                              void* d_out, int out_size, void* d_ws, size_t ws_size,
                              hipStream_t stream){
  (void)in_sizes; (void)n_in; (void)out_size; (void)ws_size;
  const float* x      = (const float*)d_in[0];
  const float* u      = (const float*)d_in[1];
  const float* ctxm   = (const float*)d_in[2];
  const float* lctx   = (const float*)d_in[3];
  const float* se_w1  = (const float*)d_in[4];
  const float* se_b1  = (const float*)d_in[5];
  const float* se_w2  = (const float*)d_in[6];
  const float* se_b2  = (const float*)d_in[7];
  const float* ae_w1  = (const float*)d_in[8];
  const float* ae_b1  = (const float*)d_in[9];
  const float* ae_w2  = (const float*)d_in[10];
  const float* ae_b2  = (const float*)d_in[11];
  const float* ce_w1  = (const float*)d_in[12];
  const float* ce_b1  = (const float*)d_in[13];
  const float* ce_w2  = (const float*)d_in[14];
  const float* ce_b2  = (const float*)d_in[15];
  const float* lce_w1 = (const float*)d_in[16];
  const float* lce_b1 = (const float*)d_in[17];
  const float* lce_w2 = (const float*)d_in[18];
  const float* lce_b2 = (const float*)d_in[19];
  const float* dec_w1 = (const float*)d_in[20];
  const float* dec_b1 = (const float*)d_in[21];
  const float* dec_w2 = (const float*)d_in[22];
  const float* dec_b2 = (const float*)d_in[23];
  const float* wih    = (const float*)d_in[24];
  const float* bih    = (const float*)d_in[25];
  const float* whh    = (const float*)d_in[26];
  const float* bhh    = (const float*)d_in[27];
  const float* cov_w1 = (const float*)d_in[28];
  const float* cov_b1 = (const float*)d_in[29];
  const float* cov_w2 = (const float*)d_in[30];
  const float* cov_b2 = (const float*)d_in[31];

  char* ws = (char*)d_ws;
  size_t off = 0;
  auto alloc = [&](size_t sz) -> char* {
    char* p = ws + off; off = (off + sz + 255) & ~(size_t)255; return p;
  };
  short* aew2b  = (short*)alloc(208*224*2);
  short* lcew2b = (short*)alloc(208*224*2);
  short* decw1b = (short*)alloc(208*224*2);
  short* covw1b = (short*)alloc(208*224*2);
  short* decw2b = (short*)alloc(16*224*2);
  short* covw2b = (short*)alloc(16*224*2);
  short* wihab  = (short*)alloc(608*224*2);
  short* wihlb  = (short*)alloc(608*224*2);
  short* whhb   = (short*)alloc(608*224*2);
  float* sew2T  = (float*)alloc(200*200*4);
  float* cew2T  = (float*)alloc(200*200*4);
  float* wihcT  = (float*)alloc(200*608*4);
  float* aeb2p  = (float*)alloc(208*4);
  float* lceb2p = (float*)alloc(208*4);
  float* decb1p = (float*)alloc(208*4);
  float* covb1p = (float*)alloc(208*4);
  float* decb2p = (float*)alloc(16*4);
  float* covb2p = (float*)alloc(16*4);
  float* bhhp   = (float*)alloc(608*4);
  float* gic    = (float*)alloc((size_t)BSZ*608*4);
  float* h0f    = (float*)alloc((size_t)BSZ*224*4);
  float* hcar   = (float*)alloc((size_t)BSZ*224*4);
  float* ctxef  = (float*)alloc((size_t)BSZ*200*4);
  short* hidbuf = (short*)alloc((size_t)(CT+1)*BSZ*224*2);   /* 23.9 MB */
  short* gibuf  = (short*)alloc((size_t)CR*608*2);           /* 62.3 MB */

  float* outMean = (float*)d_out;
  float* outStd  = outMean + (size_t)DR*12;

  auto g1 = [](int n){ return dim3((unsigned)((n + 255)/256)); };

  /* weight conversions */
  k_cvt<<<g1(208*224), 256, 0, stream>>>(ae_w2,  aew2b,  200, 200, 200,   0, 208, 224);
  k_cvt<<<g1(208*224), 256, 0, stream>>>(lce_w2, lcew2b, 200, 200, 200,   0, 208, 224);
  k_cvt<<<g1(208*224), 256, 0, stream>>>(dec_w1, decw1b, 200, 200, 200,   0, 208, 224);
  k_cvt<<<g1(208*224), 256, 0, stream>>>(cov_w1, covw1b, 200, 200, 200,   0, 208, 224);
  k_cvt<<<g1(16*224),  256, 0, stream>>>(dec_w2, decw2b,  12, 200, 200,   0,  16, 224);
  k_cvt<<<g1(16*224),  256, 0, stream>>>(cov_w2, covw2b,  12, 200, 200,   0,  16, 224);
  k_cvt<<<g1(608*224), 256, 0, stream>>>(wih,    wihab,  600, 200, 600, 200, 608, 224);
  k_cvt<<<g1(608*224), 256, 0, stream>>>(wih,    wihlb,  600, 200, 600, 400, 608, 224);
  k_cvt<<<g1(608*224), 256, 0, stream>>>(whh,    whhb,   600, 200, 200,   0, 608, 224);
  k_cvtT<<<g1(200*200), 256, 0, stream>>>(se_w2, sew2T, 200, 200, 200, 0, 200);
  k_cvtT<<<g1(200*200), 256, 0, stream>>>(ce_w2, cew2T, 200, 200, 200, 0, 200);
  k_cvtT<<<g1(200*608), 256, 0, stream>>>(wih,   wihcT, 600, 200, 600, 0, 608);
  k_padb<<<g1(208), 256, 0, stream>>>(ae_b2,  aeb2p,  200, 208);
  k_padb<<<g1(208), 256, 0, stream>>>(lce_b2, lceb2p, 200, 208);
  k_padb<<<g1(208), 256, 0, stream>>>(dec_b1, decb1p, 200, 208);
  k_padb<<<g1(208), 256, 0, stream>>>(cov_b1, covb1p, 200, 208);
  k_padb<<<g1(16),  256, 0, stream>>>(dec_b2, decb2p,  12,  16);
  k_padb<<<g1(16),  256, 0, stream>>>(cov_b2, covb2p,  12,  16);
  k_padb<<<g1(608), 256, 0, stream>>>(bhh,    bhhp,   600, 608);

  /* batch-level embeds */
  k_mlp2<<<BSZ, 256, 0, stream>>>(x,    12, se_w1, se_b1, sew2T, se_b2, 1, h0f,   224, hidbuf);
  k_mlp2<<<BSZ, 256, 0, stream>>>(ctxm,  8, ce_w1, ce_b1, cew2T, ce_b2, 0, ctxef, 200, (short*)nullptr);
  k_gictx<<<BSZ, 256, 0, stream>>>(ctxef, wihcT, bih, gic);

  /* chunked: gi GEMM -> GRU scan -> decode heads */
  for (int c = 0; c < NCH; ++c){
    k_fuse<<<CR/64, 256, 0, stream>>>(u, lctx, ae_w1, ae_b1, lce_w1, lce_b1,
                                      aew2b, aeb2p, lcew2b, lceb2p,
                                      wihab, wihlb, gic, gibuf, c*CR);
    k_gru_c<<<BSZ/16, 512, 0, stream>>>(gibuf, (c == 0) ? h0f : hcar,
                                        whhb, bhhp, hidbuf, hcar);
    int rowStart = (c == 0) ? 0 : BSZ;
    int nRows    = (c == 0) ? (CT+1)*BSZ : CT*BSZ;
    k_dec<<<nRows/64, 256, 0, stream>>>(hidbuf, rowStart, c*CT*BSZ,
                                        decw1b, decb1p, decw2b, decb2p,
                                        covw1b, covb1p, covw2b, covb2p,
                                        outMean, outStd);
  }
}

// Round 3
// 1444.251 us; speedup vs baseline: 1.3709x; 1.3709x over previous
//
#include <hip/hip_runtime.h>
#include <math.h>

#define TT   100
#define BSZ  2048
#define NCH  4
#define CT   (TT/NCH)        /* 25 steps per chunk */
#define CR   (CT*BSZ)        /* 51200 (t,b) rows per chunk */
#define DR   ((TT+1)*BSZ)
#define EPSV 1e-4f

typedef short bfrag __attribute__((ext_vector_type(8)));  /* 8 bf16 (4 VGPR) */
typedef float facc  __attribute__((ext_vector_type(4)));  /* 4 f32 acc */

static __device__ __forceinline__ short f2b(float x){
  union { float f; unsigned u; } c; c.f = x;
  unsigned r = (c.u + 0x7FFFu + ((c.u >> 16) & 1u)) >> 16;   /* RNE */
  return (short)r;
}
static __device__ __forceinline__ float b2f(short s){
  union { unsigned u; float f; } c; c.u = ((unsigned)(unsigned short)s) << 16;
  return c.f;
}
static __device__ __forceinline__ facc mfma16(bfrag a, bfrag b, facc c){
  return __builtin_amdgcn_mfma_f32_16x16x32_bf16(a, b, c, 0, 0, 0);
}
static __device__ __forceinline__ float sigm(float x){ return 1.f/(1.f+__expf(-x)); }
static __device__ __forceinline__ float tanh_f(float x){
  x = fminf(fmaxf(x, -15.f), 15.f);
  float e = __expf(2.f*x);
  return (e-1.f)/(e+1.f);
}

/* ---------------- prep kernels ---------------- */
__global__ __launch_bounds__(256) void k_cvt(const float* __restrict__ src, short* __restrict__ dst,
    int N, int K, int stride, int colOff, int Np, int Kp){
  int idx = blockIdx.x*256 + threadIdx.x;
  if (idx >= Np*Kp) return;
  int n = idx / Kp, k = idx - n*Kp;
  float v = (n < N && k < K) ? src[(size_t)n*stride + colOff + k] : 0.f;
  dst[idx] = f2b(v);
}
__global__ __launch_bounds__(256) void k_cvtT(const float* __restrict__ src, float* __restrict__ dst,
    int N, int K, int stride, int colOff, int Np){
  int idx = blockIdx.x*256 + threadIdx.x;
  if (idx >= K*Np) return;
  int k = idx / Np, n = idx - k*Np;
  dst[idx] = (n < N) ? src[(size_t)n*stride + colOff + k] : 0.f;
}
__global__ __launch_bounds__(256) void k_padb(const float* __restrict__ src, float* __restrict__ dst,
    int N, int Np){
  int idx = blockIdx.x*256 + threadIdx.x;
  if (idx < Np) dst[idx] = (idx < N) ? src[idx] : 0.f;
}

/* ---------------- small two-layer MLP over BS rows (VALU fp32) ---------------- */
__global__ __launch_bounds__(256) void k_mlp2(const float* __restrict__ x, int Kin,
    const float* __restrict__ w1, const float* __restrict__ b1,
    const float* __restrict__ w2T, const float* __restrict__ b2,
    int act_tanh,
    float* __restrict__ outf, int outf_stride,
    short* __restrict__ outb){
  int row = blockIdx.x, t = threadIdx.x;
  __shared__ float xr[16];
  __shared__ float h1[200];
  if (t < Kin) xr[t] = x[(size_t)row*Kin + t];
  __syncthreads();
  if (t < 200){
    float a = b1[t];
    #pragma unroll 4
    for (int i = 0; i < Kin; ++i) a += xr[i] * w1[t*Kin + i];
    h1[t] = fmaxf(a, 0.f);
  }
  __syncthreads();
  if (t < 224){
    float v = 0.f;
    if (t < 200){
      float a = b2[t];
      #pragma unroll 4
      for (int k = 0; k < 200; ++k) a += h1[k] * w2T[k*200 + t];
      v = act_tanh ? tanh_f(a) : fmaxf(a, 0.f);
    }
    if (t < outf_stride) outf[(size_t)row*outf_stride + t] = v;
    if (outb) outb[(size_t)row*224 + t] = f2b(v);
  }
}

/* gi_ctx[b][n] = bih[n] + sum_k ctx_embed[b][k] * wih[n][k]  (ctx cols 0..199) */
__global__ __launch_bounds__(256) void k_gictx(const float* __restrict__ ctxe,
    const float* __restrict__ wT, const float* __restrict__ bih, float* __restrict__ gic){
  int b = blockIdx.x, t = threadIdx.x;
  __shared__ float cr[200];
  if (t < 200) cr[t] = ctxe[(size_t)b*200 + t];
  __syncthreads();
  for (int n = t; n < 608; n += 256){
    float a = 0.f;
    if (n < 600){
      a = bih[n];
      #pragma unroll 4
      for (int k = 0; k < 200; ++k) a += cr[k] * wT[k*608 + n];
    }
    gic[(size_t)b*608 + n] = a;
  }
}

/* ---------------- fused: L1(VALU) -> L2(MFMA, in-place LDS) -> gi GEMM ----------------
   64 (t,b) rows per block, one T-chunk per launch.
   t1 leading dim padded 224->232 shorts (464B stride: 8 banks x 2 lanes = conflict-free).
   Stage 4: 10 col-groups of 4 n-tiles (1/wave); acc -> LDS stg -> coalesced short2 stores. */
__global__ __launch_bounds__(256) void k_fuse(
    const float* __restrict__ u, const float* __restrict__ lc,
    const float* __restrict__ aw1, const float* __restrict__ ab1,
    const float* __restrict__ lw1, const float* __restrict__ lb1,
    const short* __restrict__ aw2b, const float* __restrict__ ab2p,
    const short* __restrict__ lw2b, const float* __restrict__ lb2p,
    const short* __restrict__ wihab, const short* __restrict__ wihlb,
    const float* __restrict__ gic, short* __restrict__ gibuf, int rowBase){
  __shared__ short t1[2][64][232];
  __shared__ float stg[64][66];
  int tid = threadIdx.x;
  int r0 = blockIdx.x * 64;           /* chunk-local row */
  /* stage 1: both L1s, fp32 VALU -> LDS bf16 (K padded with zeros) */
  for (int e = tid; e < 64*232; e += 256){
    int row = e / 232, k = e - row*232;
    float va = 0.f, vl = 0.f;
    if (k < 200){
      size_t rg = (size_t)rowBase + r0 + row;
      const float* ur = u + rg*4;
      const float* lr = lc + rg*6;
      va = ab1[k];
      #pragma unroll
      for (int i = 0; i < 4; ++i) va += ur[i]*aw1[k*4+i];
      va = fmaxf(va, 0.f);
      vl = lb1[k];
      #pragma unroll
      for (int i = 0; i < 6; ++i) vl += lr[i]*lw1[k*6+i];
      vl = fmaxf(vl, 0.f);
    }
    t1[0][row][k] = f2b(va);
    t1[1][row][k] = f2b(vl);
  }
  __syncthreads();
  int w = tid >> 6, lane = tid & 63, lm = lane & 15, lq = lane >> 4;
  /* stages 2/3: L2 MFMA for each chain, results written back in place */
  for (int ch = 0; ch < 2; ++ch){
    const short* w2b = ch ? lw2b : aw2b;
    const float* b2p = ch ? lb2p : ab2p;
    int nt0 = (w == 0) ? 0 : 4 + 3*(w-1);
    int cnt = (w == 0) ? 4 : 3;
    facc accT[4][4];
    #pragma unroll
    for (int ti = 0; ti < 4; ++ti)
      #pragma unroll
      for (int m = 0; m < 4; ++m)
        accT[ti][m] = (facc){0.f,0.f,0.f,0.f};
    #pragma unroll
    for (int ti = 0; ti < 4; ++ti) if (ti < cnt){
      int col = (nt0+ti)*16 + lm;
      #pragma unroll
      for (int ks = 0; ks < 7; ++ks){
        bfrag bf = *reinterpret_cast<const bfrag*>(&w2b[(size_t)col*224 + ks*32 + lq*8]);
        #pragma unroll
        for (int m = 0; m < 4; ++m){
          bfrag af = *reinterpret_cast<const bfrag*>(&t1[ch][m*16 + lm][ks*32 + lq*8]);
          accT[ti][m] = mfma16(af, bf, accT[ti][m]);
        }
      }
    }
    __syncthreads();   /* all reads of t1[ch] complete -> safe to overwrite */
    #pragma unroll
    for (int ti = 0; ti < 4; ++ti) if (ti < cnt){
      int col = (nt0+ti)*16 + lm;
      float bias = b2p[col];
      #pragma unroll
      for (int m = 0; m < 4; ++m)
        #pragma unroll
        for (int i = 0; i < 4; ++i)
          t1[ch][m*16 + lq*4 + i][col] = f2b(fmaxf(accT[ti][m][i] + bias, 0.f));
    }
    __syncthreads();
  }
  /* stage 4: gi = ae2 @ WihA^T + lce2 @ WihL^T + gi_ctx, LDS-staged coalesced output */
  int b0 = (int)(((size_t)rowBase + r0) & 2047);   /* 64-aligned, no wrap within block */
  for (int g = 0; g < 10; ++g){
    int nt = g*4 + w;
    if (nt < 38){
      int col = nt*16 + lm;
      bfrag Ba[7], Bl[7];
      #pragma unroll
      for (int ks = 0; ks < 7; ++ks){
        Ba[ks] = *reinterpret_cast<const bfrag*>(&wihab[(size_t)col*224 + ks*32 + lq*8]);
        Bl[ks] = *reinterpret_cast<const bfrag*>(&wihlb[(size_t)col*224 + ks*32 + lq*8]);
      }
      facc acc[4];
      #pragma unroll
      for (int m = 0; m < 4; ++m) acc[m] = (facc){0.f,0.f,0.f,0.f};
      #pragma unroll
      for (int m = 0; m < 4; ++m){
        #pragma unroll
        for (int ks = 0; ks < 7; ++ks){
          bfrag a = *reinterpret_cast<const bfrag*>(&t1[0][m*16 + lm][ks*32 + lq*8]);
          acc[m] = mfma16(a, Ba[ks], acc[m]);
        }
        #pragma unroll
        for (int ks = 0; ks < 7; ++ks){
          bfrag a = *reinterpret_cast<const bfrag*>(&t1[1][m*16 + lm][ks*32 + lq*8]);
          acc[m] = mfma16(a, Bl[ks], acc[m]);
        }
      }
      #pragma unroll
      for (int m = 0; m < 4; ++m)
        #pragma unroll
        for (int i = 0; i < 4; ++i)
          stg[m*16 + lq*4 + i][w*16 + lm] = acc[m][i];
    }
    __syncthreads();
    int colBase = g*64;
    int nCols = 608 - colBase; if (nCols > 64) nCols = 64;   /* last group: 32 */
    int nS2 = nCols >> 1;
    for (int idx = tid; idx < 64*nS2; idx += 256){
      int row = idx / nS2, c2 = idx - row*nS2;
      int c = c2*2;
      const float* gr = gic + (size_t)(b0+row)*608 + colBase + c;
      float v0 = stg[row][c]   + gr[0];
      float v1 = stg[row][c+1] + gr[1];
      union { short s[2]; unsigned uu; } pk;
      pk.s[0] = f2b(v0); pk.s[1] = f2b(v1);
      *reinterpret_cast<unsigned*>(&gibuf[((size_t)r0+row)*608 + colBase + c]) = pk.uu;
    }
    __syncthreads();
  }
}

/* ---------------- GRU scan chunk: 128 blocks x 512 thr, 16 batch rows/block ----------------
   W_hh fragments persistent in registers; h fp32 in LDS across steps. */
__global__ __launch_bounds__(512, 2) void k_gru_c(
    const short* __restrict__ gib, const float* __restrict__ hin,
    const short* __restrict__ whhb, const float* __restrict__ bhhp,
    short* __restrict__ hidb, float* __restrict__ hout){
  __shared__ float gh[16][608];
  __shared__ float hF[16][200];
  __shared__ short hB[16][224];
  int tid = threadIdx.x;
  int r0 = blockIdx.x * 16;
  int w = tid >> 6, lane = tid & 63, lm = lane & 15, lq = lane >> 4;
  int ntStart = (w < 6) ? w*5 : 30 + (w-6)*4;
  int ntCnt   = (w < 6) ? 5 : 4;
  bfrag B[5][7];
  float bias[5];
  #pragma unroll
  for (int s = 0; s < 5; ++s) if (s < ntCnt){
    int col = (ntStart+s)*16 + lm;
    bias[s] = bhhp[col];
    #pragma unroll
    for (int ks = 0; ks < 7; ++ks)
      B[s][ks] = *reinterpret_cast<const bfrag*>(&whhb[(size_t)col*224 + ks*32 + lq*8]);
  }
  for (int e = tid; e < 16*224; e += 512){
    int row = e / 224, k = e - row*224;
    float v = hin[(size_t)(r0+row)*224 + k];
    if (k < 200) hF[row][k] = v;
    hB[row][k] = f2b(v);
  }
  __syncthreads();
  for (int t = 0; t < CT; ++t){
    /* prefetch gi for this step */
    float pr[7], pz[7], pn[7];
    #pragma unroll
    for (int i = 0; i < 7; ++i){
      int e = tid + i*512;
      if (e < 3200){
        int row = e / 200, j = e - row*200;
        size_t base = ((size_t)t*BSZ + r0 + row)*608 + j;
        pr[i] = b2f(gib[base]);
        pz[i] = b2f(gib[base+200]);
        pn[i] = b2f(gib[base+400]);
      }
    }
    /* gh = h @ whh^T + bhh */
    bfrag hf[7];
    #pragma unroll
    for (int ks = 0; ks < 7; ++ks)
      hf[ks] = *reinterpret_cast<const bfrag*>(&hB[lm][ks*32 + lq*8]);
    #pragma unroll
    for (int s = 0; s < 5; ++s) if (s < ntCnt){
      facc a = {0.f,0.f,0.f,0.f};
      #pragma unroll
      for (int ks = 0; ks < 7; ++ks) a = mfma16(hf[ks], B[s][ks], a);
      int col = (ntStart+s)*16 + lm;
      #pragma unroll
      for (int i = 0; i < 4; ++i) gh[lq*4 + i][col] = a[i] + bias[s];
    }
    __syncthreads();
    /* gates */
    #pragma unroll
    for (int i = 0; i < 7; ++i){
      int e = tid + i*512;
      if (e < 3200){
        int row = e / 200, j = e - row*200;
        float r = sigm(pr[i] + gh[row][j]);
        float zz = sigm(pz[i] + gh[row][200+j]);
        float n = tanh_f(pn[i] + r * gh[row][400+j]);
        float hn = (1.f - zz)*n + zz*hF[row][j];
        hF[row][j] = hn;
        short hb = f2b(hn);
        hB[row][j] = hb;
        hidb[((size_t)(t+1)*BSZ + r0 + row)*224 + j] = hb;
      }
    }
    __syncthreads();
  }
  /* write carry h (fp32, padded) for next chunk */
  for (int e = tid; e < 16*224; e += 512){
    int row = e / 224, k = e - row*224;
    hout[(size_t)(r0+row)*224 + k] = (k < 200) ? hF[row][k] : 0.f;
  }
}

/* ---------------- fused decode + cov heads over one chunk of hiddens ---------------- */
__global__ __launch_bounds__(256) void k_dec(
    const short* __restrict__ hidb, int rowStart, int outBase,
    const short* __restrict__ dw1b, const float* __restrict__ db1p,
    const short* __restrict__ dw2b, const float* __restrict__ db2p,
    const short* __restrict__ cw1b, const float* __restrict__ cb1p,
    const short* __restrict__ cw2b, const float* __restrict__ cb2p,
    float* __restrict__ outMean, float* __restrict__ outStd){
  __shared__ short h1t[64][224];
  int tid = threadIdx.x;
  int r0 = rowStart + blockIdx.x * 64;     /* local row in hidb */
  int w = tid >> 6, lane = tid & 63, lm = lane & 15, lq = lane >> 4;
  for (int e = tid; e < 64*16; e += 256)
    h1t[e >> 4][208 + (e & 15)] = 0;
  bfrag hf[4][7];
  #pragma unroll
  for (int m = 0; m < 4; ++m)
    #pragma unroll
    for (int ks = 0; ks < 7; ++ks)
      hf[m][ks] = *reinterpret_cast<const bfrag*>(&hidb[(size_t)(r0 + m*16 + lm)*224 + ks*32 + lq*8]);
  int ntStart = (w == 0) ? 0 : 4 + 3*(w-1);
  int ntCnt   = (w == 0) ? 4 : 3;
  for (int pass = 0; pass < 2; ++pass){
    const short* w1b = pass ? cw1b : dw1b;
    const float* b1p = pass ? cb1p : db1p;
    const short* w2b = pass ? cw2b : dw2b;
    const float* b2p = pass ? cb2p : db2p;
    __syncthreads();
    for (int nti = 0; nti < ntCnt; ++nti){
      int nt = ntStart + nti;
      int col = nt*16 + lm;
      facc z = {0.f,0.f,0.f,0.f};
      facc acc[4] = {z,z,z,z};
      #pragma unroll
      for (int ks = 0; ks < 7; ++ks){
        bfrag bf = *reinterpret_cast<const bfrag*>(&w1b[(size_t)col*224 + ks*32 + lq*8]);
        #pragma unroll
        for (int m = 0; m < 4; ++m) acc[m] = mfma16(hf[m][ks], bf, acc[m]);
      }
      float bias = b1p[col];
      #pragma unroll
      for (int m = 0; m < 4; ++m)
        #pragma unroll
        for (int i = 0; i < 4; ++i)
          h1t[m*16 + lq*4 + i][col] = f2b(fmaxf(acc[m][i] + bias, 0.f));
    }
    __syncthreads();
    bfrag a2[7];
    #pragma unroll
    for (int ks = 0; ks < 7; ++ks)
      a2[ks] = *reinterpret_cast<const bfrag*>(&h1t[w*16 + lm][ks*32 + lq*8]);
    facc acc = {0.f,0.f,0.f,0.f};
    #pragma unroll
    for (int ks = 0; ks < 7; ++ks){
      bfrag bf = *reinterpret_cast<const bfrag*>(&w2b[(size_t)lm*224 + ks*32 + lq*8]);
      acc = mfma16(a2[ks], bf, acc);
    }
    if (lm < 12){
      float bias = b2p[lm];
      #pragma unroll
      for (int i = 0; i < 4; ++i){
        size_t rg = (size_t)outBase + r0 + w*16 + lq*4 + i;
        float v = acc[i] + bias;
        if (pass){
          float sp = (v > 15.f) ? v : log1pf(__expf(v));
          outStd[rg*12 + lm] = sqrtf(sp + EPSV);
        } else {
          outMean[rg*12 + lm] = v;
        }
      }
    }
  }
}

extern "C" void kernel_launch(void* const* d_in, const int* in_sizes, int n_in,
                              void* d_out, int out_size, void* d_ws, size_t ws_size,
                              hipStream_t stream){
  (void)in_sizes; (void)n_in; (void)out_size; (void)ws_size;
  const float* x      = (const float*)d_in[0];
  const float* u      = (const float*)d_in[1];
  const float* ctxm   = (const float*)d_in[2];
  const float* lctx   = (const float*)d_in[3];
  const float* se_w1  = (const float*)d_in[4];
  const float* se_b1  = (const float*)d_in[5];
  const float* se_w2  = (const float*)d_in[6];
  const float* se_b2  = (const float*)d_in[7];
  const float* ae_w1  = (const float*)d_in[8];
  const float* ae_b1  = (const float*)d_in[9];
  const float* ae_w2  = (const float*)d_in[10];
  const float* ae_b2  = (const float*)d_in[11];
  const float* ce_w1  = (const float*)d_in[12];
  const float* ce_b1  = (const float*)d_in[13];
  const float* ce_w2  = (const float*)d_in[14];
  const float* ce_b2  = (const float*)d_in[15];
  const float* lce_w1 = (const float*)d_in[16];
  const float* lce_b1 = (const float*)d_in[17];
  const float* lce_w2 = (const float*)d_in[18];
  const float* lce_b2 = (const float*)d_in[19];
  const float* dec_w1 = (const float*)d_in[20];
  const float* dec_b1 = (const float*)d_in[21];
  const float* dec_w2 = (const float*)d_in[22];
  const float* dec_b2 = (const float*)d_in[23];
  const float* wih    = (const float*)d_in[24];
  const float* bih    = (const float*)d_in[25];
  const float* whh    = (const float*)d_in[26];
  const float* bhh    = (const float*)d_in[27];
  const float* cov_w1 = (const float*)d_in[28];
  const float* cov_b1 = (const float*)d_in[29];
  const float* cov_w2 = (const float*)d_in[30];
  const float* cov_b2 = (const float*)d_in[31];

  char* ws = (char*)d_ws;
  size_t off = 0;
  auto alloc = [&](size_t sz) -> char* {
    char* p = ws + off; off = (off + sz + 255) & ~(size_t)255; return p;
  };
  short* aew2b  = (short*)alloc(208*224*2);
  short* lcew2b = (short*)alloc(208*224*2);
  short* decw1b = (short*)alloc(208*224*2);
  short* covw1b = (short*)alloc(208*224*2);
  short* decw2b = (short*)alloc(16*224*2);
  short* covw2b = (short*)alloc(16*224*2);
  short* wihab  = (short*)alloc(608*224*2);
  short* wihlb  = (short*)alloc(608*224*2);
  short* whhb   = (short*)alloc(608*224*2);
  float* sew2T  = (float*)alloc(200*200*4);
  float* cew2T  = (float*)alloc(200*200*4);
  float* wihcT  = (float*)alloc(200*608*4);
  float* aeb2p  = (float*)alloc(208*4);
  float* lceb2p = (float*)alloc(208*4);
  float* decb1p = (float*)alloc(208*4);
  float* covb1p = (float*)alloc(208*4);
  float* decb2p = (float*)alloc(16*4);
  float* covb2p = (float*)alloc(16*4);
  float* bhhp   = (float*)alloc(608*4);
  float* gic    = (float*)alloc((size_t)BSZ*608*4);
  float* h0f    = (float*)alloc((size_t)BSZ*224*4);
  float* hcar   = (float*)alloc((size_t)BSZ*224*4);
  float* ctxef  = (float*)alloc((size_t)BSZ*200*4);
  short* hidbuf = (short*)alloc((size_t)(CT+1)*BSZ*224*2);   /* 23.9 MB */
  short* gibuf  = (short*)alloc((size_t)CR*608*2);           /* 62.3 MB */

  float* outMean = (float*)d_out;
  float* outStd  = outMean + (size_t)DR*12;

  auto g1 = [](int n){ return dim3((unsigned)((n + 255)/256)); };

  /* weight conversions */
  k_cvt<<<g1(208*224), 256, 0, stream>>>(ae_w2,  aew2b,  200, 200, 200,   0, 208, 224);
  k_cvt<<<g1(208*224), 256, 0, stream>>>(lce_w2, lcew2b, 200, 200, 200,   0, 208, 224);
  k_cvt<<<g1(208*224), 256, 0, stream>>>(dec_w1, decw1b, 200, 200, 200,   0, 208, 224);
  k_cvt<<<g1(208*224), 256, 0, stream>>>(cov_w1, covw1b, 200, 200, 200,   0, 208, 224);
  k_cvt<<<g1(16*224),  256, 0, stream>>>(dec_w2, decw2b,  12, 200, 200,   0,  16, 224);
  k_cvt<<<g1(16*224),  256, 0, stream>>>(cov_w2, covw2b,  12, 200, 200,   0,  16, 224);
  k_cvt<<<g1(608*224), 256, 0, stream>>>(wih,    wihab,  600, 200, 600, 200, 608, 224);
  k_cvt<<<g1(608*224), 256, 0, stream>>>(wih,    wihlb,  600, 200, 600, 400, 608, 224);
  k_cvt<<<g1(608*224), 256, 0, stream>>>(whh,    whhb,   600, 200, 200,   0, 608, 224);
  k_cvtT<<<g1(200*200), 256, 0, stream>>>(se_w2, sew2T, 200, 200, 200, 0, 200);
  k_cvtT<<<g1(200*200), 256, 0, stream>>>(ce_w2, cew2T, 200, 200, 200, 0, 200);
  k_cvtT<<<g1(200*608), 256, 0, stream>>>(wih,   wihcT, 600, 200, 600, 0, 608);
  k_padb<<<g1(208), 256, 0, stream>>>(ae_b2,  aeb2p,  200, 208);
  k_padb<<<g1(208), 256, 0, stream>>>(lce_b2, lceb2p, 200, 208);
  k_padb<<<g1(208), 256, 0, stream>>>(dec_b1, decb1p, 200, 208);
  k_padb<<<g1(208), 256, 0, stream>>>(cov_b1, covb1p, 200, 208);
  k_padb<<<g1(16),  256, 0, stream>>>(dec_b2, decb2p,  12,  16);
  k_padb<<<g1(16),  256, 0, stream>>>(cov_b2, covb2p,  12,  16);
  k_padb<<<g1(608), 256, 0, stream>>>(bhh,    bhhp,   600, 608);

  /* batch-level embeds */
  k_mlp2<<<BSZ, 256, 0, stream>>>(x,    12, se_w1, se_b1, sew2T, se_b2, 1, h0f,   224, hidbuf);
  k_mlp2<<<BSZ, 256, 0, stream>>>(ctxm,  8, ce_w1, ce_b1, cew2T, ce_b2, 0, ctxef, 200, (short*)nullptr);
  k_gictx<<<BSZ, 256, 0, stream>>>(ctxef, wihcT, bih, gic);

  /* chunked: gi GEMM -> GRU scan -> decode heads */
  for (int c = 0; c < NCH; ++c){
    k_fuse<<<CR/64, 256, 0, stream>>>(u, lctx, ae_w1, ae_b1, lce_w1, lce_b1,
                                      aew2b, aeb2p, lcew2b, lceb2p,
                                      wihab, wihlb, gic, gibuf, c*CR);
    k_gru_c<<<BSZ/16, 512, 0, stream>>>(gibuf, (c == 0) ? h0f : hcar,
                                        whhb, bhhp, hidbuf, hcar);
    int rowStart = (c == 0) ? 0 : BSZ;
    int nRows    = (c == 0) ? (CT+1)*BSZ : CT*BSZ;
    k_dec<<<nRows/64, 256, 0, stream>>>(hidbuf, rowStart, c*CT*BSZ,
                                        decw1b, decb1p, decw2b, decb2p,
                                        covw1b, covb1p, covw2b, covb2p,
                                        outMean, outStd);
  }
}